// Round 2
// baseline (902.564 us; speedup 1.0000x reference)
//
#include <hip/hip_runtime.h>
#include <stdint.h>

typedef __attribute__((ext_vector_type(8))) short short8;
typedef __attribute__((ext_vector_type(16))) float f32x16;
typedef __attribute__((ext_vector_type(4))) unsigned short ushort4v;

static __device__ __forceinline__ unsigned short f2bf(float f) {
  union { float f; unsigned u; } v; v.f = f;
  unsigned r = v.u + 0x7fffu + ((v.u >> 16) & 1u);
  return (unsigned short)(r >> 16);
}

// ---------------- prep: W -> bf16 MFMA B-fragment layout (32x32x16) ----------------
// layout: [c][s][gt(32)][ks(64)][lane(64)][8] bf16
// B-frag: lane l holds col g = gt*32 + (l&31), k = ks*16 + (l>>5)*8 + e
__global__ __launch_bounds__(256) void prep_w(const float* __restrict__ Wa,
                                              const float* __restrict__ Wb,
                                              const float* __restrict__ Wc,
                                              unsigned short* __restrict__ wfrag) {
  int t  = blockIdx.x * 256 + threadIdx.x;
  int l  = t & 63;
  int ks = (t >> 6) & 63;
  int gt = (t >> 12) & 31;
  int s  = (t >> 17) & 1;
  int c  = t >> 18;
  const float* W = (c == 0) ? Wa : (c == 1) ? Wb : Wc;
  int g  = gt * 32 + (l & 31);
  int k0 = ks * 16 + ((l >> 5) * 8);
  const float* src = W + (size_t)s * 1048576 + (size_t)k0 * 1024 + g;
  unsigned short* dst = wfrag + (size_t)t * 8;
#pragma unroll
  for (int e = 0; e < 8; ++e) dst[e] = f2bf(src[(size_t)e * 1024]);
}

// ---------------- prep: softmax A, Aoff frags (32x32x16 A-layout), diag, BN affine ----------------
__global__ __launch_bounds__(256) void prep_misc(
    const float* e0, const int* a0, const float* b0, const float* g0, const float* be0, const float* rm0, const float* rv0,
    const float* e1, const int* a1, const float* b1, const float* g1, const float* be1, const float* rm1, const float* rv1,
    const float* e2, const int* a2, const float* b2, const float* g2, const float* be2, const float* rm2, const float* rv2,
    unsigned short* __restrict__ aofrag, float* __restrict__ diagA,
    float* __restrict__ scale2, float* __restrict__ shift2) {
  __shared__ float A[64][64];
  int c = blockIdx.x;
  int tid = threadIdx.x;
  const float* ev = (c==0)?e0:(c==1)?e1:e2;
  const int*   ad = (c==0)?a0:(c==1)?a1:a2;
  const float* bb = (c==0)?b0:(c==1)?b1:b2;
  const float* gm = (c==0)?g0:(c==1)?g1:g2;
  const float* bt = (c==0)?be0:(c==1)?be1:be2;
  const float* rm = (c==0)?rm0:(c==1)?rm1:rm2;
  const float* rv = (c==0)?rv0:(c==1)?rv1:rv2;
  if (tid < 64) {
    int n = tid;
    float mx = -3.0e38f;
    for (int m = 0; m < 64; ++m) {
      float lg = (ad[n*64+m] > 0) ? ev[n*64+m] : -9.0e15f;
      A[n][m] = lg; mx = fmaxf(mx, lg);
    }
    float ssum = 0.f;
    for (int m = 0; m < 64; ++m) { float p = __expf(A[n][m] - mx); A[n][m] = p; ssum += p; }
    float inv = 1.f / ssum;
    for (int m = 0; m < 64; ++m) A[n][m] *= inv;
  }
  __syncthreads();
  if (tid < 64) diagA[c*64 + tid] = A[tid][tid];
  // Aoff in 32x32x16 A-frag layout: [nt(2)][ks(4)][lane(64)][8]
  for (int idx = tid; idx < 4096; idx += 256) {
    int e  = idx & 7;
    int l  = (idx >> 3) & 63;
    int ks = (idx >> 9) & 3;
    int nt = idx >> 11;
    int n = nt*32 + (l & 31);
    int m = ks*16 + ((l >> 5) * 8) + e;
    float vv = (m == n) ? 0.f : A[n][m];
    aofrag[c*4096 + idx] = f2bf(vv);
  }
  for (int g = tid; g < 1024; g += 256) {
    float sc = gm[g] * rsqrtf(rv[g] + 1e-5f);
    scale2[c*1024 + g] = sc;
    shift2[c*1024 + g] = bt[g] + (bb[g] - rm[g]) * sc;
  }
}

// ---------------- staging helpers ----------------
template<int CH>
__device__ __forceinline__ void stage_load(float4* st, const float* xb0, const float* xb1,
                                           int tid, int kt) {
#pragma unroll
  for (int e2 = 0; e2 < 8; ++e2) {
    int p4 = (tid + e2 * 256) * 4;          // 0..8188, 2 views x 4096 floats
    const float* vb = (p4 < 4096) ? xb0 : xb1;
    int o = p4 & 4095;
    if (CH == 0) {
      st[e2] = *(const float4*)(vb + kt*4096 + o);
    } else if (CH == 1) {
      int i = o >> 7, fl = o & 127;
      st[e2] = *(const float4*)(vb + i*1024 + kt*128 + fl);
    } else {
      int jj = o >> 10, i = (o >> 5) & 31, k = o & 31;
      st[e2] = *(const float4*)(vb + (kt*4 + jj)*1024 + i*32 + k);
    }
  }
}

template<int CH>
__device__ __forceinline__ void stage_write(char* dst, const float4* st, int tid) {
#pragma unroll
  for (int e2 = 0; e2 < 8; ++e2) {
    int p4 = (tid + e2 * 256) * 4;
    int o = p4 & 4095;
    int vbase = (p4 >> 12) * 32;
    float4 val = st[e2];
    if (CH == 0) {
      int i0 = o & 31, fl = o >> 5;
      float vv[4] = {val.x, val.y, val.z, val.w};
#pragma unroll
      for (int j = 0; j < 4; ++j) {
        int row = vbase + i0 + j;
        int byt = (row*256 + fl*2) ^ ((row & 15) << 4);
        *(unsigned short*)(dst + byt) = f2bf(vv[j]);
      }
    } else {
      int row, fl;
      if (CH == 1) { row = vbase + (o >> 7); fl = o & 127; }
      else         { row = vbase + ((o >> 5) & 31); fl = (o >> 10)*32 + (o & 31); }
      ushort4v w; w.x = f2bf(val.x); w.y = f2bf(val.y); w.z = f2bf(val.z); w.w = f2bf(val.w);
      int byt = (row*256 + fl*2) ^ ((row & 15) << 4);
      *(ushort4v*)(dst + byt) = w;
    }
  }
}

// ---------------- main fused channel kernel (32x32x16 MFMA, dbuf LDS) ----------------
// CH=0: x-off = f*32 + i    out-off = g*32 + i                       (weight 0.5, write)
// CH=1: x-off = i*1024 + f  out-off = i*1024 + g                     (weight 0.25, add)
// CH=2: x-off = (f>>5)*1024 + i*32 + (f&31)
//       out-off = (g>>5)*1024 + i*32 + (g&31)                        (weight 0.25, add)
template<int CH>
__global__ __launch_bounds__(256, 3) void gconv(
    const float* __restrict__ x, const int* __restrict__ idxp,
    const unsigned short* __restrict__ wfrag, const unsigned short* __restrict__ aofrag,
    const float* __restrict__ diagA, const float* __restrict__ scale2,
    const float* __restrict__ shift2, float* __restrict__ out) {
  __shared__ alignas(128) char lds[32768];   // 2 x 16KB x-tile [64 rows][128 k] bf16, XOR-swizzled
  int tid  = threadIdx.x;
  int lane = tid & 63;
  int wave = tid >> 6;
  int bid  = blockIdx.x;
  // XCD-affinity swizzle: all 8 feature-slices of a graph land on the same XCD
  int graph = (bid & 7) + ((bid >> 6) << 3);   // 0..511
  int slice = (bid >> 3) & 7;
  int b = graph >> 3, v = graph & 7;
  int v2 = idxp[v];
  const float* xb0 = x + (size_t)(b*8 + v)  * 32768;
  const float* xb1 = x + (size_t)(b*8 + v2) * 32768;

  f32x16 acc[2][2];   // [s][mt]
#pragma unroll
  for (int s = 0; s < 2; ++s)
#pragma unroll
    for (int mt = 0; mt < 2; ++mt)
#pragma unroll
      for (int r = 0; r < 16; ++r) acc[s][mt][r] = 0.f;

  int gt  = slice*4 + wave;        // global 32-col tile index, 0..31
  int l31 = lane & 31;
  int lh  = lane >> 5;
  int swz = (l31 & 15) << 4;

  // W fragment base pointers (stride per ks-step = 64 short8 = 1KB)
  const short8* w0p = (const short8*)(wfrag + ((size_t)(      gt) * 4096 + lane) * 8);
  const short8* w1p = (const short8*)(wfrag + ((size_t)(32  + gt) * 4096 + lane) * 8);

  {
    float4 st[8];
    stage_load<CH>(st, xb0, xb1, tid, 0);
    stage_write<CH>(lds, st, tid);
  }
  __syncthreads();

  for (int kt = 0; kt < 8; ++kt) {
    char* cur = lds + (kt & 1) * 16384;
    char* nxt = lds + ((kt & 1) ^ 1) * 16384;
    float4 st[8];
    if (kt < 7) stage_load<CH>(st, xb0, xb1, tid, kt + 1);
#pragma unroll
    for (int ks = 0; ks < 8; ++ks) {
      int ksg = kt*8 + ks;
      short8 bf0 = w0p[(size_t)ksg * 64];
      short8 bf1 = w1p[(size_t)ksg * 64];
      int byt0 = (ks*32 + lh*16) ^ swz;
      short8 a0 = *(const short8*)(cur + l31*256 + byt0);
      short8 a1 = *(const short8*)(cur + 8192 + l31*256 + byt0);
      acc[0][0] = __builtin_amdgcn_mfma_f32_32x32x16_bf16(a0, bf0, acc[0][0], 0, 0, 0);
      acc[0][1] = __builtin_amdgcn_mfma_f32_32x32x16_bf16(a1, bf0, acc[0][1], 0, 0, 0);
      acc[1][0] = __builtin_amdgcn_mfma_f32_32x32x16_bf16(a0, bf1, acc[1][0], 0, 0, 0);
      acc[1][1] = __builtin_amdgcn_mfma_f32_32x32x16_bf16(a1, bf1, acc[1][1], 0, 0, 0);
    }
    if (kt < 7) stage_write<CH>(nxt, st, tid);
    __syncthreads();
  }

  // ---- epilogue: H1 -> LDS (B-frag order), agg = Aoff @ H1, BN + ReLU + pair-mean ----
  char* hb = lds + wave * 4096;          // per-wave [32 g][64 m] bf16, swizzled
  int swzg = (l31 & 7) << 4;
#pragma unroll
  for (int mt = 0; mt < 2; ++mt)
#pragma unroll
    for (int rq = 0; rq < 4; ++rq) {
      ushort4v w;
      w.x = f2bf(acc[1][mt][rq*4+0]); w.y = f2bf(acc[1][mt][rq*4+1]);
      w.z = f2bf(acc[1][mt][rq*4+2]); w.w = f2bf(acc[1][mt][rq*4+3]);
      int byt = (l31*128 + (mt*64 + rq*16 + lh*8)) ^ swzg;
      *(ushort4v*)(hb + byt) = w;
    }
  __syncthreads();

  f32x16 agg[2];
#pragma unroll
  for (int nt = 0; nt < 2; ++nt)
#pragma unroll
    for (int r = 0; r < 16; ++r) agg[nt][r] = 0.f;

#pragma unroll
  for (int ks = 0; ks < 4; ++ks) {
    int byt = (l31*128 + ks*32 + lh*16) ^ swzg;
    short8 hf = *(const short8*)(hb + byt);
#pragma unroll
    for (int nt = 0; nt < 2; ++nt) {
      short8 aof = *(const short8*)((const char*)aofrag + (size_t)((nt*4 + ks)*64 + lane) * 16);
      agg[nt] = __builtin_amdgcn_mfma_f32_32x32x16_bf16(aof, hf, agg[nt], 0, 0, 0);
    }
  }

  int g = gt*32 + l31;
  float sc = scale2[g], sh = shift2[g];
  size_t obase = (size_t)graph * 32768;
#pragma unroll
  for (int rq = 0; rq < 4; ++rq) {
    int i0 = rq*8 + lh*4;
    float4 d0 = *(const float4*)(diagA + i0);
    float4 d1 = *(const float4*)(diagA + 32 + i0);
    const float* d0p = (const float*)&d0;
    const float* d1p = (const float*)&d1;
    float res[4];
#pragma unroll
    for (int j = 0; j < 4; ++j) {
      int r = rq*4 + j;
      float va = d0p[j] * acc[0][0][r] + agg[0][r];
      float vb = d1p[j] * acc[0][1][r] + agg[1][r];
      va = fmaxf(va * sc + sh, 0.f);
      vb = fmaxf(vb * sc + sh, 0.f);
      res[j] = 0.5f * (va + vb);
    }
    if (CH == 0) {
      float4 o4;
      o4.x = 0.5f*res[0]; o4.y = 0.5f*res[1]; o4.z = 0.5f*res[2]; o4.w = 0.5f*res[3];
      *(float4*)(out + obase + (size_t)g*32 + i0) = o4;
    } else if (CH == 1) {
#pragma unroll
      for (int j = 0; j < 4; ++j) {
        float* p = out + obase + (size_t)(i0 + j)*1024 + g;
        *p += 0.25f * res[j];
      }
    } else {
#pragma unroll
      for (int j = 0; j < 4; ++j) {
        float* p = out + obase + (size_t)(g >> 5)*1024 + (size_t)(i0 + j)*32 + (g & 31);
        *p += 0.25f * res[j];
      }
    }
  }
}

extern "C" void kernel_launch(void* const* d_in, const int* in_sizes, int n_in,
                              void* d_out, int out_size, void* d_ws, size_t ws_size,
                              hipStream_t stream) {
  (void)in_sizes; (void)n_in; (void)out_size; (void)ws_size;
  const float* x    = (const float*)d_in[0];
  const int*   idx  = (const int*)d_in[1];
  const int*   adj1 = (const int*)d_in[2];
  const int*   adj2 = (const int*)d_in[3];
  const float *W[3], *e[3], *bb[3], *gm[3], *bt[3], *rm[3], *rv[3];
  for (int c = 0; c < 3; ++c) {
    int base = 4 + c*7;
    W[c]  = (const float*)d_in[base + 0];
    e[c]  = (const float*)d_in[base + 1];
    bb[c] = (const float*)d_in[base + 2];
    gm[c] = (const float*)d_in[base + 3];
    bt[c] = (const float*)d_in[base + 4];
    rm[c] = (const float*)d_in[base + 5];
    rv[c] = (const float*)d_in[base + 6];
  }
  char* ws = (char*)d_ws;
  unsigned short* wfrag  = (unsigned short*)ws;                    // 3 * 2,097,152 bf16 = 12 MB
  unsigned short* aofrag = (unsigned short*)(ws + 12582912);       // 3 * 4096 bf16
  float* diagA  = (float*)(ws + 12607488);                         // 3 * 64 f32
  float* scale2 = (float*)(ws + 12608256);                         // 3 * 1024 f32
  float* shift2 = (float*)(ws + 12620544);                         // 3 * 1024 f32

  prep_w<<<3072, 256, 0, stream>>>(W[0], W[1], W[2], wfrag);
  prep_misc<<<3, 256, 0, stream>>>(
      e[0], adj1, bb[0], gm[0], bt[0], rm[0], rv[0],
      e[1], adj2, bb[1], gm[1], bt[1], rm[1], rv[1],
      e[2], adj2, bb[2], gm[2], bt[2], rm[2], rv[2],
      aofrag, diagA, scale2, shift2);

  float* out = (float*)d_out;
  gconv<0><<<4096, 256, 0, stream>>>(x, idx, wfrag,           aofrag,        diagA,       scale2,        shift2,        out);
  gconv<1><<<4096, 256, 0, stream>>>(x, idx, wfrag + 2097152, aofrag + 4096, diagA + 64,  scale2 + 1024, shift2 + 1024, out);
  gconv<2><<<4096, 256, 0, stream>>>(x, idx, wfrag + 4194304, aofrag + 8192, diagA + 128, scale2 + 2048, shift2 + 2048, out);
}

// Round 3
// 644.350 us; speedup vs baseline: 1.4007x; 1.4007x over previous
//
#include <hip/hip_runtime.h>
#include <stdint.h>

typedef __attribute__((ext_vector_type(8))) short short8;
typedef __attribute__((ext_vector_type(16))) float f32x16;
typedef __attribute__((ext_vector_type(4))) float f32x4;
typedef __attribute__((ext_vector_type(4))) unsigned short ushort4v;

union S8 { short8 v; unsigned short u[8]; };

static __device__ __forceinline__ unsigned short f2bf(float f) {
  union { float f; unsigned u; } v; v.f = f;
  unsigned r = v.u + 0x7fffu + ((v.u >> 16) & 1u);
  return (unsigned short)(r >> 16);
}

static __device__ __forceinline__ void glds16(const void* g, void* l) {
  __builtin_amdgcn_global_load_lds(
      (const __attribute__((address_space(1))) unsigned int*)g,
      (__attribute__((address_space(3))) unsigned int*)l, 16, 0, 0);
}

// ---------------- prep: W -> glds-ready per-(g8,kt) 32KB images ----------------
// element t = ((((c*8+g8)*16+kt)*4+ks)*8+tt)*64+lane ; tt = s*4+gt
// value = W_c[s][k = kt*64+ks*16+(lane>>5)*8+e][g = g8*128+gt*32+(lane&31)]
__global__ __launch_bounds__(256) void prep_w(const float* __restrict__ Wa,
                                              const float* __restrict__ Wb,
                                              const float* __restrict__ Wc,
                                              unsigned short* __restrict__ wfrag) {
  int t    = blockIdx.x * 256 + threadIdx.x;
  int lane = t & 63;
  int tt   = (t >> 6) & 7;
  int ks   = (t >> 9) & 3;
  int kt   = (t >> 11) & 15;
  int g8   = (t >> 15) & 7;
  int c    = t >> 18;
  const float* W = (c == 0) ? Wa : (c == 1) ? Wb : Wc;
  int s  = tt >> 2, gt = tt & 3;
  int g  = g8*128 + gt*32 + (lane & 31);
  int k0 = kt*64 + ks*16 + ((lane >> 5) * 8);
  const float* src = W + (size_t)s * 1048576 + (size_t)k0 * 1024 + g;
  unsigned short* dst = wfrag + (size_t)t * 8;
#pragma unroll
  for (int e = 0; e < 8; ++e) dst[e] = f2bf(src[(size_t)e * 1024]);
}

// ---------------- prep: softmax A, Aoff frags (32x32x16 A-layout), diag, BN affine ----------------
__global__ __launch_bounds__(256) void prep_misc(
    const float* e0, const int* a0, const float* b0, const float* g0, const float* be0, const float* rm0, const float* rv0,
    const float* e1, const int* a1, const float* b1, const float* g1, const float* be1, const float* rm1, const float* rv1,
    const float* e2, const int* a2, const float* b2, const float* g2, const float* be2, const float* rm2, const float* rv2,
    unsigned short* __restrict__ aofrag, float* __restrict__ diagA,
    float* __restrict__ scale2, float* __restrict__ shift2) {
  __shared__ float A[64][64];
  int c = blockIdx.x;
  int tid = threadIdx.x;
  const float* ev = (c==0)?e0:(c==1)?e1:e2;
  const int*   ad = (c==0)?a0:(c==1)?a1:a2;
  const float* bb = (c==0)?b0:(c==1)?b1:b2;
  const float* gm = (c==0)?g0:(c==1)?g1:g2;
  const float* bt = (c==0)?be0:(c==1)?be1:be2;
  const float* rm = (c==0)?rm0:(c==1)?rm1:rm2;
  const float* rv = (c==0)?rv0:(c==1)?rv1:rv2;
  if (tid < 64) {
    int n = tid;
    float mx = -3.0e38f;
    for (int m = 0; m < 64; ++m) {
      float lg = (ad[n*64+m] > 0) ? ev[n*64+m] : -9.0e15f;
      A[n][m] = lg; mx = fmaxf(mx, lg);
    }
    float ssum = 0.f;
    for (int m = 0; m < 64; ++m) { float p = __expf(A[n][m] - mx); A[n][m] = p; ssum += p; }
    float inv = 1.f / ssum;
    for (int m = 0; m < 64; ++m) A[n][m] *= inv;
  }
  __syncthreads();
  if (tid < 64) diagA[c*64 + tid] = A[tid][tid];
  // Aoff in 32x32x16 A-frag layout: [nt(2)][ks(4)][lane(64)][8]
  for (int idx = tid; idx < 4096; idx += 256) {
    int e  = idx & 7;
    int l  = (idx >> 3) & 63;
    int ks = (idx >> 9) & 3;
    int nt = idx >> 11;
    int n = nt*32 + (l & 31);
    int m = ks*16 + ((l >> 5) * 8) + e;
    float vv = (m == n) ? 0.f : A[n][m];
    aofrag[c*4096 + idx] = f2bf(vv);
  }
  for (int g = tid; g < 1024; g += 256) {
    float sc = gm[g] * rsqrtf(rv[g] + 1e-5f);
    scale2[c*1024 + g] = sc;
    shift2[c*1024 + g] = bt[g] + (bb[g] - rm[g]) * sc;
  }
}

// ---------------- A staging loads (per-thread 32 f32 of the A-tile) ----------------
// thread owns frag slots (ks=0..3, mt=wave, lane); node row = (wave&1)*32 + (lane&31)
template<int CH>
__device__ __forceinline__ void loadA(float av[4][8], const float* __restrict__ sview,
                                      int d0, int lh, int kt) {
#pragma unroll
  for (int ks = 0; ks < 4; ++ks) {
    int kb = kt*64 + ks*16 + lh*8;
    if (CH == 0) {
#pragma unroll
      for (int e = 0; e < 8; ++e) av[ks][e] = sview[(size_t)(kb + e)*32 + d0];
    } else if (CH == 1) {
      const float* sp = sview + d0*1024 + kb;
      *(float4*)&av[ks][0] = *(const float4*)sp;
      *(float4*)&av[ks][4] = *(const float4*)(sp + 4);
    } else {
      const float* sp = sview + (kb >> 5)*1024 + d0*32 + (kb & 31);
      *(float4*)&av[ks][0] = *(const float4*)sp;
      *(float4*)&av[ks][4] = *(const float4*)(sp + 4);
    }
  }
}

// ---------------- main fused channel kernel ----------------
// block: 128 m-rows (2 graphs) x [128 g x 2 s], BK=64, 16 k-steps
// grid: bid = mp*8 + g8  (identity -> g8 has XCD affinity, W images L2-resident)
template<int CH>
__global__ __launch_bounds__(256, 2) void gconv(
    const float* __restrict__ x, const int* __restrict__ idxp,
    const unsigned short* __restrict__ wimg, const unsigned short* __restrict__ aofrag,
    const float* __restrict__ diagA, const float* __restrict__ scale2,
    const float* __restrict__ shift2, float* __restrict__ out) {
  __shared__ alignas(128) char lds[65536];   // main: A[0,16K) + B[16K,48K); epilogue: H1[0,32K)+H0x[32K,64K)
  char* ldsB = lds + 16384;
  int tid = threadIdx.x, lane = tid & 63, wave = tid >> 6;
  int l31 = lane & 31, lh = lane >> 5;
  int wm = wave >> 1, sn = wave & 1;

  int bid = blockIdx.x;
  int g8 = bid & 7, mp = bid >> 3;
  int graphA = mp*2;

  // staging role: this thread stages rows of graph (wave>>1), view-half (wave&1)
  int sgraph = graphA + wm;
  int sb = sgraph >> 3, sv = sgraph & 7;
  const float* sview = x + (size_t)(sb*8 + (sn ? idxp[sv] : sv)) * 32768;
  int d0 = l31;

  f32x16 acc[2][4];
#pragma unroll
  for (int mt = 0; mt < 2; ++mt)
#pragma unroll
    for (int gt = 0; gt < 4; ++gt)
#pragma unroll
      for (int r = 0; r < 16; ++r) acc[mt][gt][r] = 0.f;

  alignas(16) float av[4][8];
  loadA<CH>(av, sview, d0, lh, 0);

  const char* imgbase = (const char*)wimg + ((size_t)g8 * 16) * 32768 + wave*8192 + lane*16;
  char* gdst = ldsB + wave*8192;

  for (int kt = 0; kt < 16; ++kt) {
    // stage B via global_load_lds (lane-linear image)
    {
      const char* src = imgbase + (size_t)kt * 32768;
#pragma unroll
      for (int j = 0; j < 8; ++j) glds16(src + j*1024, gdst + j*1024);
    }
    // convert + write A frags
#pragma unroll
    for (int ks = 0; ks < 4; ++ks) {
      S8 pk;
#pragma unroll
      for (int e = 0; e < 8; ++e) pk.u[e] = f2bf(av[ks][e]);
      *(short8*)(lds + ((ks*4 + wave)*64 + lane)*16) = pk.v;
    }
    __syncthreads();
    // MFMA phase
#pragma unroll
    for (int ks = 0; ks < 4; ++ks) {
      short8 a0 = *(const short8*)(lds + ((ks*4 + wm*2    )*64 + lane)*16);
      short8 a1 = *(const short8*)(lds + ((ks*4 + wm*2 + 1)*64 + lane)*16);
      const char* bbp = ldsB + ((size_t)((ks*8 + sn*4)*64 + lane))*16;
#pragma unroll
      for (int gt = 0; gt < 4; ++gt) {
        short8 bf = *(const short8*)(bbp + gt*1024);
        acc[0][gt] = __builtin_amdgcn_mfma_f32_32x32x16_bf16(a0, bf, acc[0][gt], 0, 0, 0);
        acc[1][gt] = __builtin_amdgcn_mfma_f32_32x32x16_bf16(a1, bf, acc[1][gt], 0, 0, 0);
      }
    }
    if (kt < 15) loadA<CH>(av, sview, d0, lh, kt + 1);
    asm volatile("" ::: "memory");
    __builtin_amdgcn_s_barrier();     // raw: keep A-prefetch in flight
    asm volatile("" ::: "memory");
  }

  // ---- epilogue ----
  // stash: sn==1 waves write H1 (bf16 col-major, swizzled) ; sn==0 waves export H0 g-half-1 (f32)
  if (sn == 1) {
    char* basep = lds + wm*16384;
#pragma unroll
    for (int gt = 0; gt < 4; ++gt) {
      int col = gt*32 + l31;
      char* cb = basep + col*128;
      int cs = (col & 7) << 4;
#pragma unroll
      for (int mt2 = 0; mt2 < 2; ++mt2)
#pragma unroll
        for (int j = 0; j < 4; ++j) {
          ushort4v pk;
          pk.x = f2bf(acc[mt2][gt][4*j+0]);
          pk.y = f2bf(acc[mt2][gt][4*j+1]);
          pk.z = f2bf(acc[mt2][gt][4*j+2]);
          pk.w = f2bf(acc[mt2][gt][4*j+3]);
          int r2 = mt2*64 + j*16 + lh*8;
          *(ushort4v*)(cb + (r2 ^ cs)) = pk;
        }
    }
  } else {
    char* ebase = lds + 32768 + wm*16384;
#pragma unroll
    for (int mt2 = 0; mt2 < 2; ++mt2)
#pragma unroll
      for (int t2 = 0; t2 < 2; ++t2)
#pragma unroll
        for (int q4 = 0; q4 < 4; ++q4)
          *(f32x4*)(ebase + (size_t)(((mt2*2 + t2)*4) + q4)*1024 + lane*16) =
              ((const f32x4*)&acc[mt2][2 + t2])[q4];
  }
  __syncthreads();

  // agg = Aoff @ H1 for (graph wm, g-half sn)
  f32x16 agg[2][2];
#pragma unroll
  for (int nta = 0; nta < 2; ++nta)
#pragma unroll
    for (int gl = 0; gl < 2; ++gl)
#pragma unroll
      for (int r = 0; r < 16; ++r) agg[nta][gl][r] = 0.f;

#pragma unroll
  for (int ks = 0; ks < 4; ++ks) {
#pragma unroll
    for (int gl = 0; gl < 2; ++gl) {
      int col = (sn*2 + gl)*32 + l31;
      int cs = (col & 7) << 4;
      short8 hf = *(const short8*)(lds + wm*16384 + col*128 + ((ks*32 + lh*16) ^ cs));
#pragma unroll
      for (int nta = 0; nta < 2; ++nta) {
        short8 aof = *(const short8*)((const char*)aofrag + (size_t)((nta*4 + ks)*64 + lane)*16);
        agg[nta][gl] = __builtin_amdgcn_mfma_f32_32x32x16_bf16(aof, hf, agg[nta][gl], 0, 0, 0);
      }
    }
  }

  // H0 for my g-half
  f32x16 h0[2][2];
  if (sn == 0) {
    h0[0][0] = acc[0][0]; h0[0][1] = acc[0][1];
    h0[1][0] = acc[1][0]; h0[1][1] = acc[1][1];
  } else {
    const char* ebase = lds + 32768 + wm*16384;
#pragma unroll
    for (int mt2 = 0; mt2 < 2; ++mt2)
#pragma unroll
      for (int t2 = 0; t2 < 2; ++t2)
#pragma unroll
        for (int q4 = 0; q4 < 4; ++q4)
          ((f32x4*)&h0[mt2][t2])[q4] =
              *(const f32x4*)(ebase + (size_t)(((mt2*2 + t2)*4) + q4)*1024 + lane*16);
  }

  // combine + BN + ReLU + pair-mean + scatter
  int graph_id = graphA + wm;
  size_t obase = (size_t)graph_id * 32768;
#pragma unroll
  for (int gl = 0; gl < 2; ++gl) {
    int g = g8*128 + sn*64 + gl*32 + l31;
    float sc = scale2[g], sh = shift2[g];
#pragma unroll
    for (int j = 0; j < 4; ++j) {
      int i0 = j*8 + lh*4;
      float4 dA = *(const float4*)(diagA + i0);
      float4 dB = *(const float4*)(diagA + 32 + i0);
      float res[4];
#pragma unroll
      for (int jj = 0; jj < 4; ++jj) {
        int q = j*4 + jj;
        float da = ((const float*)&dA)[jj], db = ((const float*)&dB)[jj];
        float va = da * h0[0][gl][q] + agg[0][gl][q];
        float vb = db * h0[1][gl][q] + agg[1][gl][q];
        va = fmaxf(va * sc + sh, 0.f);
        vb = fmaxf(vb * sc + sh, 0.f);
        res[jj] = 0.5f * (va + vb);
      }
      if (CH == 0) {
        float4 o4;
        o4.x = 0.5f*res[0]; o4.y = 0.5f*res[1]; o4.z = 0.5f*res[2]; o4.w = 0.5f*res[3];
        *(float4*)(out + obase + (size_t)g*32 + i0) = o4;
      } else if (CH == 1) {
#pragma unroll
        for (int jj = 0; jj < 4; ++jj)
          out[obase + (size_t)(i0 + jj)*1024 + g] += 0.25f * res[jj];
      } else {
#pragma unroll
        for (int jj = 0; jj < 4; ++jj)
          out[obase + (size_t)(g >> 5)*1024 + (size_t)(i0 + jj)*32 + (g & 31)] += 0.25f * res[jj];
      }
    }
  }
}

extern "C" void kernel_launch(void* const* d_in, const int* in_sizes, int n_in,
                              void* d_out, int out_size, void* d_ws, size_t ws_size,
                              hipStream_t stream) {
  (void)in_sizes; (void)n_in; (void)out_size; (void)ws_size;
  const float* x    = (const float*)d_in[0];
  const int*   idx  = (const int*)d_in[1];
  const int*   adj1 = (const int*)d_in[2];
  const int*   adj2 = (const int*)d_in[3];
  const float *W[3], *e[3], *bb[3], *gm[3], *bt[3], *rm[3], *rv[3];
  for (int c = 0; c < 3; ++c) {
    int base = 4 + c*7;
    W[c]  = (const float*)d_in[base + 0];
    e[c]  = (const float*)d_in[base + 1];
    bb[c] = (const float*)d_in[base + 2];
    gm[c] = (const float*)d_in[base + 3];
    bt[c] = (const float*)d_in[base + 4];
    rm[c] = (const float*)d_in[base + 5];
    rv[c] = (const float*)d_in[base + 6];
  }
  char* ws = (char*)d_ws;
  unsigned short* wfrag  = (unsigned short*)ws;                    // 3 * 2,097,152 bf16 = 12 MB
  unsigned short* aofrag = (unsigned short*)(ws + 12582912);       // 3 * 4096 bf16
  float* diagA  = (float*)(ws + 12607488);                         // 3 * 64 f32
  float* scale2 = (float*)(ws + 12608256);                         // 3 * 1024 f32
  float* shift2 = (float*)(ws + 12620544);                         // 3 * 1024 f32

  prep_w<<<3072, 256, 0, stream>>>(W[0], W[1], W[2], wfrag);
  prep_misc<<<3, 256, 0, stream>>>(
      e[0], adj1, bb[0], gm[0], bt[0], rm[0], rv[0],
      e[1], adj2, bb[1], gm[1], bt[1], rm[1], rv[1],
      e[2], adj2, bb[2], gm[2], bt[2], rm[2], rv[2],
      aofrag, diagA, scale2, shift2);

  float* out = (float*)d_out;
  gconv<0><<<2048, 256, 0, stream>>>(x, idx, wfrag,           aofrag,        diagA,       scale2,        shift2,        out);
  gconv<1><<<2048, 256, 0, stream>>>(x, idx, wfrag + 2097152, aofrag + 4096, diagA + 64,  scale2 + 1024, shift2 + 1024, out);
  gconv<2><<<2048, 256, 0, stream>>>(x, idx, wfrag + 4194304, aofrag + 8192, diagA + 128, scale2 + 2048, shift2 + 2048, out);
}

// Round 4
// 575.439 us; speedup vs baseline: 1.5685x; 1.1198x over previous
//
#include <hip/hip_runtime.h>
#include <stdint.h>

typedef __attribute__((ext_vector_type(8))) short short8;
typedef __attribute__((ext_vector_type(16))) float f32x16;
typedef __attribute__((ext_vector_type(4))) float f32x4;
typedef __attribute__((ext_vector_type(4))) unsigned short ushort4v;

union S8 { short8 v; unsigned short u[8]; };

static __device__ __forceinline__ unsigned short f2bf(float f) {
  union { float f; unsigned u; } v; v.f = f;
  unsigned r = v.u + 0x7fffu + ((v.u >> 16) & 1u);
  return (unsigned short)(r >> 16);
}

static __device__ __forceinline__ void glds16(const void* g, void* l) {
  __builtin_amdgcn_global_load_lds(
      (const __attribute__((address_space(1))) unsigned int*)g,
      (__attribute__((address_space(3))) unsigned int*)l, 16, 0, 0);
}

// ---------------- prep: W -> glds-ready per-(g8,kt32) 16KB images ----------------
// t = ((((c*8+g8)*32+kt)*2+ks)*8+tt)*64+lane ; tt = s*4+gt
// value = W_c[s][k = kt*32+ks*16+(lane>>5)*8+e][g = g8*128+gt*32+(lane&31)]
__global__ __launch_bounds__(256) void prep_w(const float* __restrict__ Wa,
                                              const float* __restrict__ Wb,
                                              const float* __restrict__ Wc,
                                              unsigned short* __restrict__ wfrag) {
  int t    = blockIdx.x * 256 + threadIdx.x;
  int lane = t & 63;
  int tt   = (t >> 6) & 7;
  int ks   = (t >> 9) & 1;
  int kt   = (t >> 10) & 31;
  int g8   = (t >> 15) & 7;
  int c    = t >> 18;
  const float* W = (c == 0) ? Wa : (c == 1) ? Wb : Wc;
  int s  = tt >> 2, gt = tt & 3;
  int g  = g8*128 + gt*32 + (lane & 31);
  int k0 = kt*32 + ks*16 + ((lane >> 5) * 8);
  const float* src = W + (size_t)s * 1048576 + (size_t)k0 * 1024 + g;
  unsigned short* dst = wfrag + (size_t)t * 8;
#pragma unroll
  for (int e = 0; e < 8; ++e) dst[e] = f2bf(src[(size_t)e * 1024]);
}

// ---------------- prep: softmax A, Aoff frags (32x32x16 A-layout), diag, BN affine ----------------
__global__ __launch_bounds__(256) void prep_misc(
    const float* e0, const int* a0, const float* b0, const float* g0, const float* be0, const float* rm0, const float* rv0,
    const float* e1, const int* a1, const float* b1, const float* g1, const float* be1, const float* rm1, const float* rv1,
    const float* e2, const int* a2, const float* b2, const float* g2, const float* be2, const float* rm2, const float* rv2,
    unsigned short* __restrict__ aofrag, float* __restrict__ diagA,
    float* __restrict__ scale2, float* __restrict__ shift2) {
  __shared__ float A[64][64];
  int c = blockIdx.x;
  int tid = threadIdx.x;
  const float* ev = (c==0)?e0:(c==1)?e1:e2;
  const int*   ad = (c==0)?a0:(c==1)?a1:a2;
  const float* bb = (c==0)?b0:(c==1)?b1:b2;
  const float* gm = (c==0)?g0:(c==1)?g1:g2;
  const float* bt = (c==0)?be0:(c==1)?be1:be2;
  const float* rm = (c==0)?rm0:(c==1)?rm1:rm2;
  const float* rv = (c==0)?rv0:(c==1)?rv1:rv2;
  if (tid < 64) {
    int n = tid;
    float mx = -3.0e38f;
    for (int m = 0; m < 64; ++m) {
      float lg = (ad[n*64+m] > 0) ? ev[n*64+m] : -9.0e15f;
      A[n][m] = lg; mx = fmaxf(mx, lg);
    }
    float ssum = 0.f;
    for (int m = 0; m < 64; ++m) { float p = __expf(A[n][m] - mx); A[n][m] = p; ssum += p; }
    float inv = 1.f / ssum;
    for (int m = 0; m < 64; ++m) A[n][m] *= inv;
  }
  __syncthreads();
  if (tid < 64) diagA[c*64 + tid] = A[tid][tid];
  // Aoff in 32x32x16 A-frag layout: [nt(2)][ks(4)][lane(64)][8]
  for (int idx = tid; idx < 4096; idx += 256) {
    int e  = idx & 7;
    int l  = (idx >> 3) & 63;
    int ks = (idx >> 9) & 3;
    int nt = idx >> 11;
    int n = nt*32 + (l & 31);
    int m = ks*16 + ((l >> 5) * 8) + e;
    float vv = (m == n) ? 0.f : A[n][m];
    aofrag[c*4096 + idx] = f2bf(vv);
  }
  for (int g = tid; g < 1024; g += 256) {
    float sc = gm[g] * rsqrtf(rv[g] + 1e-5f);
    scale2[c*1024 + g] = sc;
    shift2[c*1024 + g] = bt[g] + (bb[g] - rm[g]) * sc;
  }
}

// ---------------- A staging loads (per-thread 16 f32 of the next A-tile) ----------------
template<int CH>
__device__ __forceinline__ void loadA(float av[2][8], const float* __restrict__ sview,
                                      int d0, int lh, int kt) {
#pragma unroll
  for (int ks = 0; ks < 2; ++ks) {
    int kb = kt*32 + ks*16 + lh*8;
    if (CH == 0) {
#pragma unroll
      for (int e = 0; e < 8; ++e) av[ks][e] = sview[(size_t)(kb + e)*32 + d0];
    } else if (CH == 1) {
      const float* sp = sview + d0*1024 + kb;
      *(float4*)&av[ks][0] = *(const float4*)sp;
      *(float4*)&av[ks][4] = *(const float4*)(sp + 4);
    } else {
      const float* sp = sview + kt*1024 + d0*32 + ks*16 + lh*8;
      *(float4*)&av[ks][0] = *(const float4*)sp;
      *(float4*)&av[ks][4] = *(const float4*)(sp + 4);
    }
  }
}

// ---------------- main fused channel kernel ----------------
// block: 128 m-rows (2 graphs) x [128 g x 2 s], BK=32, 32 k-steps, dbuf A+B, 1 barrier/kt
// grid: bid = mp*8 + g8  (g8 has XCD affinity -> W images L2-resident)
template<int CH>
__global__ __launch_bounds__(256, 2) void gconv(
    const float* __restrict__ x, const int* __restrict__ idxp,
    const unsigned short* __restrict__ wimg, const unsigned short* __restrict__ aofrag,
    const float* __restrict__ diagA, const float* __restrict__ scale2,
    const float* __restrict__ shift2, float* __restrict__ out) {
  __shared__ alignas(128) char lds[65536];   // main: A dbuf [0,16K) + B dbuf [16K,48K); epilogue: H1[0,32K)+H0x[32K,64K)
  char* ldsB = lds + 16384;
  int tid = threadIdx.x, lane = tid & 63, wave = tid >> 6;
  int l31 = lane & 31, lh = lane >> 5;
  int wm = wave >> 1, sn = wave & 1;

  int bid = blockIdx.x;
  int g8 = bid & 7, mp = bid >> 3;
  int graphA = mp*2;

  // staging role: wave stages rows of graph (wave>>1), view-half (wave&1)
  int sgraph = graphA + wm;
  int sb = sgraph >> 3, sv = sgraph & 7;
  const float* sview = x + (size_t)(sb*8 + (sn ? idxp[sv] : sv)) * 32768;
  int d0 = l31;

  f32x16 acc[2][4];
#pragma unroll
  for (int mt = 0; mt < 2; ++mt)
#pragma unroll
    for (int gt = 0; gt < 4; ++gt)
#pragma unroll
      for (int r = 0; r < 16; ++r) acc[mt][gt][r] = 0.f;

  alignas(16) float av[2][8];
  const char* imgbase = (const char*)wimg + (size_t)g8 * 524288 + wave*4096 + lane*16;
  char* gdst0 = ldsB + wave*4096;

  // prologue: A[0]+B[0] into buf0, prefetch A[1] to regs
  loadA<CH>(av, sview, d0, lh, 0);
#pragma unroll
  for (int ks = 0; ks < 2; ++ks) {
    S8 pk;
#pragma unroll
    for (int e = 0; e < 8; ++e) pk.u[e] = f2bf(av[ks][e]);
    *(short8*)(lds + ((ks*4 + wave)*64 + lane)*16) = pk.v;
  }
#pragma unroll
  for (int j = 0; j < 4; ++j) glds16(imgbase + j*1024, gdst0 + j*1024);
  loadA<CH>(av, sview, d0, lh, 1);
  __syncthreads();

  for (int kt = 0; kt < 32; ++kt) {
    int p = kt & 1;
    if (kt < 31) {
      // stage B[kt+1] into bufB[p^1] (consumed after NEXT barrier)
      const char* src = imgbase + (size_t)(kt + 1) * 16384;
      char* gdst = ldsB + (p ^ 1) * 16384 + wave*4096;
#pragma unroll
      for (int j = 0; j < 4; ++j) glds16(src + j*1024, gdst + j*1024);
      // write A[kt+1] frags (from regs) into bufA[p^1]
#pragma unroll
      for (int ks = 0; ks < 2; ++ks) {
        S8 pk;
#pragma unroll
        for (int e = 0; e < 8; ++e) pk.u[e] = f2bf(av[ks][e]);
        *(short8*)(lds + (p ^ 1)*8192 + ((ks*4 + wave)*64 + lane)*16) = pk.v;
      }
      // prefetch A[kt+2] to regs
      int kt2 = (kt + 2 > 31) ? 31 : (kt + 2);
      loadA<CH>(av, sview, d0, lh, kt2);
    }
    __builtin_amdgcn_sched_barrier(0);   // keep staging issued before compute
    // MFMA phase on buf p
    {
      const char* bA = lds + p*8192;
      const char* bB = ldsB + p*16384;
      __builtin_amdgcn_s_setprio(1);
#pragma unroll
      for (int ks = 0; ks < 2; ++ks) {
        short8 a0 = *(const short8*)(bA + ((ks*4 + wm*2    )*64 + lane)*16);
        short8 a1 = *(const short8*)(bA + ((ks*4 + wm*2 + 1)*64 + lane)*16);
        const char* bbp = bB + ((size_t)((ks*8 + sn*4)*64 + lane))*16;
#pragma unroll
        for (int gt = 0; gt < 4; ++gt) {
          short8 bf = *(const short8*)(bbp + gt*1024);
          acc[0][gt] = __builtin_amdgcn_mfma_f32_32x32x16_bf16(a0, bf, acc[0][gt], 0, 0, 0);
          acc[1][gt] = __builtin_amdgcn_mfma_f32_32x32x16_bf16(a1, bf, acc[1][gt], 0, 0, 0);
        }
      }
      __builtin_amdgcn_s_setprio(0);
    }
    __syncthreads();
  }

  // ---- epilogue ----
  // sn==1 waves write H1 (bf16 col-major, swizzled); sn==0 waves export H0 g-half-1 (f32)
  if (sn == 1) {
    char* basep = lds + wm*16384;
#pragma unroll
    for (int gt = 0; gt < 4; ++gt) {
      int col = gt*32 + l31;
      char* cb = basep + col*128;
      int cs = (col & 7) << 4;
#pragma unroll
      for (int mt2 = 0; mt2 < 2; ++mt2)
#pragma unroll
        for (int j = 0; j < 4; ++j) {
          ushort4v pk;
          pk.x = f2bf(acc[mt2][gt][4*j+0]);
          pk.y = f2bf(acc[mt2][gt][4*j+1]);
          pk.z = f2bf(acc[mt2][gt][4*j+2]);
          pk.w = f2bf(acc[mt2][gt][4*j+3]);
          int r2 = mt2*64 + j*16 + lh*8;
          *(ushort4v*)(cb + (r2 ^ cs)) = pk;
        }
    }
  } else {
    char* ebase = lds + 32768 + wm*16384;
#pragma unroll
    for (int mt2 = 0; mt2 < 2; ++mt2)
#pragma unroll
      for (int t2 = 0; t2 < 2; ++t2)
#pragma unroll
        for (int q4 = 0; q4 < 4; ++q4)
          *(f32x4*)(ebase + (size_t)(((mt2*2 + t2)*4) + q4)*1024 + lane*16) =
              ((const f32x4*)&acc[mt2][2 + t2])[q4];
  }
  __syncthreads();

  // agg = Aoff @ H1 for (graph wm, g-half sn)
  f32x16 agg[2][2];
#pragma unroll
  for (int nta = 0; nta < 2; ++nta)
#pragma unroll
    for (int gl = 0; gl < 2; ++gl)
#pragma unroll
      for (int r = 0; r < 16; ++r) agg[nta][gl][r] = 0.f;

#pragma unroll
  for (int ks = 0; ks < 4; ++ks) {
#pragma unroll
    for (int gl = 0; gl < 2; ++gl) {
      int col = (sn*2 + gl)*32 + l31;
      int cs = (col & 7) << 4;
      short8 hf = *(const short8*)(lds + wm*16384 + col*128 + ((ks*32 + lh*16) ^ cs));
#pragma unroll
      for (int nta = 0; nta < 2; ++nta) {
        short8 aof = *(const short8*)((const char*)aofrag + (size_t)((nta*4 + ks)*64 + lane)*16);
        agg[nta][gl] = __builtin_amdgcn_mfma_f32_32x32x16_bf16(aof, hf, agg[nta][gl], 0, 0, 0);
      }
    }
  }

  // H0 for my g-half
  f32x16 h0[2][2];
  if (sn == 0) {
    h0[0][0] = acc[0][0]; h0[0][1] = acc[0][1];
    h0[1][0] = acc[1][0]; h0[1][1] = acc[1][1];
  } else {
    const char* ebase = lds + 32768 + wm*16384;
#pragma unroll
    for (int mt2 = 0; mt2 < 2; ++mt2)
#pragma unroll
      for (int t2 = 0; t2 < 2; ++t2)
#pragma unroll
        for (int q4 = 0; q4 < 4; ++q4)
          ((f32x4*)&h0[mt2][t2])[q4] =
              *(const f32x4*)(ebase + (size_t)(((mt2*2 + t2)*4) + q4)*1024 + lane*16);
  }

  // combine + BN + ReLU + pair-mean + scatter
  int graph_id = graphA + wm;
  size_t obase = (size_t)graph_id * 32768;
#pragma unroll
  for (int gl = 0; gl < 2; ++gl) {
    int g = g8*128 + sn*64 + gl*32 + l31;
    float sc = scale2[g], sh = shift2[g];
#pragma unroll
    for (int j = 0; j < 4; ++j) {
      int i0 = j*8 + lh*4;
      float4 dA = *(const float4*)(diagA + i0);
      float4 dB = *(const float4*)(diagA + 32 + i0);
      float res[4];
#pragma unroll
      for (int jj = 0; jj < 4; ++jj) {
        int q = j*4 + jj;
        float da = ((const float*)&dA)[jj], db = ((const float*)&dB)[jj];
        float va = da * h0[0][gl][q] + agg[0][gl][q];
        float vb = db * h0[1][gl][q] + agg[1][gl][q];
        va = fmaxf(va * sc + sh, 0.f);
        vb = fmaxf(vb * sc + sh, 0.f);
        res[jj] = 0.5f * (va + vb);
      }
      if (CH == 0) {
        float4 o4;
        o4.x = 0.5f*res[0]; o4.y = 0.5f*res[1]; o4.z = 0.5f*res[2]; o4.w = 0.5f*res[3];
        *(float4*)(out + obase + (size_t)g*32 + i0) = o4;
      } else if (CH == 1) {
#pragma unroll
        for (int jj = 0; jj < 4; ++jj)
          out[obase + (size_t)(i0 + jj)*1024 + g] += 0.25f * res[jj];
      } else {
#pragma unroll
        for (int jj = 0; jj < 4; ++jj)
          out[obase + (size_t)(g >> 5)*1024 + (size_t)(i0 + jj)*32 + (g & 31)] += 0.25f * res[jj];
      }
    }
  }
}

extern "C" void kernel_launch(void* const* d_in, const int* in_sizes, int n_in,
                              void* d_out, int out_size, void* d_ws, size_t ws_size,
                              hipStream_t stream) {
  (void)in_sizes; (void)n_in; (void)out_size; (void)ws_size;
  const float* x    = (const float*)d_in[0];
  const int*   idx  = (const int*)d_in[1];
  const int*   adj1 = (const int*)d_in[2];
  const int*   adj2 = (const int*)d_in[3];
  const float *W[3], *e[3], *bb[3], *gm[3], *bt[3], *rm[3], *rv[3];
  for (int c = 0; c < 3; ++c) {
    int base = 4 + c*7;
    W[c]  = (const float*)d_in[base + 0];
    e[c]  = (const float*)d_in[base + 1];
    bb[c] = (const float*)d_in[base + 2];
    gm[c] = (const float*)d_in[base + 3];
    bt[c] = (const float*)d_in[base + 4];
    rm[c] = (const float*)d_in[base + 5];
    rv[c] = (const float*)d_in[base + 6];
  }
  char* ws = (char*)d_ws;
  unsigned short* wfrag  = (unsigned short*)ws;                    // 3 * 2,097,152 bf16 = 12 MB
  unsigned short* aofrag = (unsigned short*)(ws + 12582912);       // 3 * 4096 bf16
  float* diagA  = (float*)(ws + 12607488);                         // 3 * 64 f32
  float* scale2 = (float*)(ws + 12608256);                         // 3 * 1024 f32
  float* shift2 = (float*)(ws + 12620544);                         // 3 * 1024 f32

  prep_w<<<3072, 256, 0, stream>>>(W[0], W[1], W[2], wfrag);
  prep_misc<<<3, 256, 0, stream>>>(
      e[0], adj1, bb[0], gm[0], bt[0], rm[0], rv[0],
      e[1], adj2, bb[1], gm[1], bt[1], rm[1], rv[1],
      e[2], adj2, bb[2], gm[2], bt[2], rm[2], rv[2],
      aofrag, diagA, scale2, shift2);

  float* out = (float*)d_out;
  gconv<0><<<2048, 256, 0, stream>>>(x, idx, wfrag,           aofrag,        diagA,       scale2,        shift2,        out);
  gconv<1><<<2048, 256, 0, stream>>>(x, idx, wfrag + 2097152, aofrag + 4096, diagA + 64,  scale2 + 1024, shift2 + 1024, out);
  gconv<2><<<2048, 256, 0, stream>>>(x, idx, wfrag + 4194304, aofrag + 8192, diagA + 128, scale2 + 2048, shift2 + 2048, out);
}